// Round 7
// baseline (493.155 us; speedup 1.0000x reference)
//
#include <hip/hip_runtime.h>

typedef __attribute__((ext_vector_type(4))) float f32x4;
typedef __attribute__((ext_vector_type(8))) short s16x8;

static __device__ __forceinline__ unsigned short f2bf(float f) {
  unsigned int u = __builtin_bit_cast(unsigned int, f);
  u += 0x7fffu + ((u >> 16) & 1u);
  return (unsigned short)(u >> 16);
}
static __device__ __forceinline__ float sigm(float x) { return 1.0f / (1.0f + __expf(-x)); }

// async global->LDS, 16B per lane. LDS dest = wave-uniform base + lane*16.
static __device__ __forceinline__ void gload16(const unsigned short* g, unsigned short* l) {
  __builtin_amdgcn_global_load_lds(
      (const __attribute__((address_space(1))) void*)g,
      (__attribute__((address_space(3))) void*)l, 16, 0, 0);
}

#define FENCE() asm volatile("" ::: "memory")
#define BAR()   { FENCE(); __builtin_amdgcn_s_barrier(); FENCE(); }
#define LGKM0() asm volatile("s_waitcnt lgkmcnt(0)" ::: "memory")

// ================= 8-phase 256^2 projection kernel (round-4 schedule) =================
// C_full[32768][2048] = A[32768][1024] @ W[2048][1024]^T, epilogue splits:
//   n<1024  -> kproj[b][m][n]; n>=1024 -> vt[b][n-1024][m] (transposed)
__global__ __launch_bounds__(512, 2) void proj_k(
    const unsigned short* __restrict__ A, const unsigned short* __restrict__ W,
    unsigned short* __restrict__ kproj, unsigned short* __restrict__ vt) {
  __shared__ unsigned short lds[2][2][2][8192];  // [buf][A/B][half][128*64]
  const int tid = threadIdx.x, lane = tid & 63, wid = tid >> 6;
  const int wm = wid >> 2, wn = wid & 3;
  // bijective XCD swizzle (nwg = 1024 = 8*128)
  const int wg = ((int)blockIdx.x & 7) * 128 + ((int)blockIdx.x >> 3);
  const int mt = wg >> 3, nt = wg & 7;
  const unsigned short* Ap = A + (long)mt * 256 * 1024;
  const unsigned short* Wp = W + (long)nt * 256 * 1024;
  const int srow = lane >> 3;                       // 0..7
  const int scol = (((lane & 7) ^ srow) << 3);      // pre-swizzled short col
  const int fr = lane & 15, fq = lane >> 4;
  const int xorv = (fr & 7) << 3;                   // read-side XOR (shorts)

#define STAGE(buf, T, h, t)                                                    \
  { const unsigned short* gp_ = (T) ? Wp : Ap;                                 \
    _Pragma("unroll") for (int p = 0; p < 2; p++) {                            \
      int r_ = wid * 16 + p * 8 + srow;                                        \
      gload16(gp_ + (long)((h) * 128 + r_) * 1024 + (long)(t) * 64 + scol,     \
              &lds[buf][T][h][(wid * 2 + p) * 512]);                           \
    } }

#define LDA_FRAG(aq)                                                           \
  { _Pragma("unroll") for (int i = 0; i < 4; i++)                              \
      _Pragma("unroll") for (int kk = 0; kk < 2; kk++)                         \
        af[i * 2 + kk] = *(const s16x8*)(Ab + ((aq) * 64 + i * 16 + fr) * 64 + \
                                         ((kk * 32 + fq * 8) ^ xorv)); }

#define LDB_FRAG(bq, arr)                                                      \
  { _Pragma("unroll") for (int j = 0; j < 2; j++)                              \
      _Pragma("unroll") for (int kk = 0; kk < 2; kk++)                         \
        arr[j * 2 + kk] = *(const s16x8*)(Bb + ((wn & 1) * 64 + ((bq) * 2 + j) * 16 + fr) * 64 + \
                                          ((kk * 32 + fq * 8) ^ xorv)); }

#define MM_Q(aq, bq, arr)                                                      \
  { __builtin_amdgcn_s_setprio(1);                                             \
    _Pragma("unroll") for (int i = 0; i < 4; i++)                              \
      _Pragma("unroll") for (int j = 0; j < 2; j++)                            \
        _Pragma("unroll") for (int kk = 0; kk < 2; kk++)                       \
          acc[(aq) * 4 + i][(bq) * 2 + j] = __builtin_amdgcn_mfma_f32_16x16x32_bf16( \
              af[i * 2 + kk], arr[j * 2 + kk], acc[(aq) * 4 + i][(bq) * 2 + j], 0, 0, 0); \
    __builtin_amdgcn_s_setprio(0); }

  f32x4 acc[8][4];
  #pragma unroll
  for (int i = 0; i < 8; i++)
    #pragma unroll
    for (int j = 0; j < 4; j++) acc[i][j] = (f32x4){0.f, 0.f, 0.f, 0.f};

  // prologue: tile0 A0,A1,B0,B1 + tile1 B0,B1
  STAGE(0, 0, 0, 0); STAGE(0, 0, 1, 0); STAGE(0, 1, 0, 0); STAGE(0, 1, 1, 0);
  STAGE(1, 1, 0, 1); STAGE(1, 1, 1, 1);
  asm volatile("s_waitcnt vmcnt(4)" ::: "memory");
  BAR();

  s16x8 af[8], b0f[4], b1f[4];
  for (int t = 0; t < 16; ++t) {
    const int pt = t & 1;
    const unsigned short* Ab = &lds[pt][0][wm][0];
    const unsigned short* Bb = &lds[pt][1][wn >> 1][0];
    // ---- phase 1: quadrant (0,0); stage A0(t+1) ----
    LDA_FRAG(0); LDB_FRAG(0, b0f);
    if (t < 15) STAGE(pt ^ 1, 0, 0, t + 1);
    BAR(); LGKM0();
    MM_Q(0, 0, b0f);
    BAR();
    // ---- phase 2: quadrant (0,1); stage A1(t+1) ----
    LDB_FRAG(1, b1f);
    if (t < 15) STAGE(pt ^ 1, 0, 1, t + 1);
    BAR(); LGKM0();
    MM_Q(0, 1, b1f);
    BAR();
    // ---- phase 3: quadrant (1,0); stage B0(t+2) ----
    LDA_FRAG(1);
    if (t < 14) STAGE(pt, 1, 0, t + 2);
    BAR(); LGKM0();
    MM_Q(1, 0, b0f);
    BAR();
    // ---- phase 4: quadrant (1,1); stage B1(t+2); counted vmcnt ----
    if (t < 14) STAGE(pt, 1, 1, t + 2);
    if (t == 14) { asm volatile("s_waitcnt vmcnt(0)" ::: "memory"); }
    else         { asm volatile("s_waitcnt vmcnt(4)" ::: "memory"); }
    BAR();
    MM_Q(1, 1, b1f);
    BAR();
  }

  // ---- epilogue: split K/V store ----
  const int nbase = nt * 256 + wn * 64;
  const bool kside = (nbase < 1024);
  #pragma unroll
  for (int i = 0; i < 8; i++) {
    const int gm0 = mt * 256 + wm * 128 + i * 16 + fq * 4;
    const int b = gm0 >> 12, mrow = gm0 & 4095;
    #pragma unroll
    for (int j = 0; j < 4; j++) {
      const int n = nbase + j * 16 + fr;
      if (kside) {
        unsigned short* dst = kproj + ((long)b * 4096 + mrow) * 1024 + n;
        #pragma unroll
        for (int q = 0; q < 4; q++) dst[(long)q * 1024] = f2bf(acc[i][j][q]);
      } else {
        ushort4 o;
        o.x = f2bf(acc[i][j][0]); o.y = f2bf(acc[i][j][1]);
        o.z = f2bf(acc[i][j][2]); o.w = f2bf(acc[i][j][3]);
        *(ushort4*)(vt + ((long)b * 1024 + (n - 1024)) * 4096 + mrow) = o;
      }
    }
  }
#undef STAGE
#undef LDA_FRAG
#undef LDB_FRAG
#undef MM_Q
}

// ---------------- rmsnorm rows of length 1024: fp32 -> bf16 (+optional raw bf16) ----------------
__global__ __launch_bounds__(256) void rmsnorm_k(const float* __restrict__ x,
                                                 const float* __restrict__ w,
                                                 unsigned short* __restrict__ y,
                                                 unsigned short* __restrict__ y_raw) {
  const int row = blockIdx.x;
  const int tid = threadIdx.x;
  const float4* xp = (const float4*)(x + (long)row * 1024);
  float4 v = xp[tid];
  float ss = v.x * v.x + v.y * v.y + v.z * v.z + v.w * v.w;
  #pragma unroll
  for (int off = 32; off; off >>= 1) ss += __shfl_xor(ss, off, 64);
  __shared__ float sb[4];
  if ((tid & 63) == 0) sb[tid >> 6] = ss;
  __syncthreads();
  float tot = sb[0] + sb[1] + sb[2] + sb[3];
  float rs = rsqrtf(tot * (1.0f / 1024.0f) + 1e-6f);
  const float4* wp = (const float4*)w;
  float4 wv = wp[tid];
  ushort4 o;
  o.x = f2bf(v.x * rs * wv.x);
  o.y = f2bf(v.y * rs * wv.y);
  o.z = f2bf(v.z * rs * wv.z);
  o.w = f2bf(v.w * rs * wv.w);
  ((ushort4*)y)[(long)row * 256 + tid] = o;
  if (y_raw) {
    ushort4 r;
    r.x = f2bf(v.x); r.y = f2bf(v.y); r.z = f2bf(v.z); r.w = f2bf(v.w);
    ((ushort4*)y_raw)[(long)row * 256 + tid] = r;
  }
}

// ---------------- fp32 -> bf16 convert (8 elems/thread) ----------------
__global__ __launch_bounds__(256) void cvt_bf16_k(const float* __restrict__ in,
                                                  unsigned short* __restrict__ out,
                                                  long n8) {
  long i = (long)blockIdx.x * 256 + threadIdx.x;
  if (i >= n8) return;
  const float4* p = (const float4*)in;
  float4 a = p[i * 2], b = p[i * 2 + 1];
  ushort4 lo, hi;
  lo.x = f2bf(a.x); lo.y = f2bf(a.y); lo.z = f2bf(a.z); lo.w = f2bf(a.w);
  hi.x = f2bf(b.x); hi.y = f2bf(b.y); hi.z = f2bf(b.z); hi.w = f2bf(b.w);
  ushort4* o = (ushort4*)out;
  o[i * 2] = lo;
  o[i * 2 + 1] = hi;
}

// ---------------- GEMM: C = alpha * A[M][K] @ W[N][K]^T (+bias) ----------------
// EPI: 0 = plain store; 2 = softmax over M(=64) -> bf16 attn + row partials;
//      3 = scale rows by 1/(rowsum(rs_part)+eps) -> bf16 (updates epilogue).
// SPLIT: K-split batching. bias2: used for odd blockIdx.z (merged gi/gh).
template <int BM, int BN, int WR, int WC, typename CT, int EPI, int SPLIT>
__global__ __launch_bounds__(WR * WC * 64) void gemm_bt(
    const unsigned short* __restrict__ A, const unsigned short* __restrict__ W,
    CT* __restrict__ C, int N, int Klen, int lda, int ldw,
    long sA, long sW, long sC, const float* __restrict__ bias,
    const float* __restrict__ bias2, float alpha, float* __restrict__ rs_part) {
  constexpr int BK = 64;
  constexpr int NT = WR * WC * 64;
  static_assert(NT == 256, "256 threads");
  constexpr int WSM = BM / WR, WSN = BN / WC;
  constexpr int MR = WSM / 16, NR = WSN / 16;
  constexpr int SEG_A = BM / 8, SEG_W = BN / 8;
  constexpr int PA = SEG_A / 4, PW = SEG_W / 4;
  static_assert(SEG_A % 4 == 0 && SEG_W % 4 == 0, "seg divisibility");
  __shared__ unsigned short As[BM * BK];
  __shared__ unsigned short Ws[BN * BK];
  __shared__ float rowinv_s[EPI == 3 ? 64 : 1];
  const int tid = threadIdx.x, lane = tid & 63, wid = tid >> 6;
  const int wr = wid / WC, wc = wid % WC;
  const int tileN = blockIdx.x * BN, tileM = blockIdx.y * BM;
  const int zb = blockIdx.z / SPLIT, zs = blockIdx.z % SPLIT;
  A += (long)zb * sA + (long)zs * Klen;
  W += (long)zb * sW + (long)zs * Klen;
  C += (long)blockIdx.z * sC;
  const float* bp = (bias2 && (blockIdx.z & 1)) ? bias2 : bias;
  const int srow = lane >> 3;
  const int scol = (lane & 7) * 8;

  if constexpr (EPI == 3) {
    // rowinv for the 64 rows of this batch: 4 threads/row, 32 partials each
    float s = 0.f;
    const float* rp = rs_part + ((long)zb * 64 + (tid >> 2)) * 128 + (tid & 3) * 32;
    #pragma unroll
    for (int i = 0; i < 32; i++) s += rp[i];
    s += __shfl_xor(s, 1, 64);
    s += __shfl_xor(s, 2, 64);
    if ((tid & 3) == 0) rowinv_s[tid >> 2] = 1.f / (s + 1e-6f);
  }

  f32x4 acc[MR][NR];
  #pragma unroll
  for (int i = 0; i < MR; i++)
    #pragma unroll
    for (int j = 0; j < NR; j++) acc[i][j] = (f32x4){0.f, 0.f, 0.f, 0.f};
  const int fr = lane & 15, fq = lane >> 4;

  for (int k0 = 0; k0 < Klen; k0 += BK) {
    #pragma unroll
    for (int p = 0; p < PA; p++) {
      int seg = wid * PA + p;
      gload16(A + (long)(tileM + seg * 8 + srow) * lda + k0 + scol, &As[seg * 512]);
    }
    #pragma unroll
    for (int p = 0; p < PW; p++) {
      int seg = wid * PW + p;
      gload16(W + (long)(tileN + seg * 8 + srow) * ldw + k0 + scol, &Ws[seg * 512]);
    }
    __syncthreads();
    #pragma unroll
    for (int kk = 0; kk < BK; kk += 32) {
      s16x8 af[MR], bf[NR];
      #pragma unroll
      for (int i = 0; i < MR; i++)
        af[i] = *(const s16x8*)(&As[(wr * WSM + i * 16 + fr) * BK + kk + fq * 8]);
      #pragma unroll
      for (int j = 0; j < NR; j++)
        bf[j] = *(const s16x8*)(&Ws[(wc * WSN + j * 16 + fr) * BK + kk + fq * 8]);
      #pragma unroll
      for (int i = 0; i < MR; i++)
        #pragma unroll
        for (int j = 0; j < NR; j++)
          acc[i][j] = __builtin_amdgcn_mfma_f32_16x16x32_bf16(af[i], bf[j], acc[i][j], 0, 0, 0);
    }
    __syncthreads();
  }

  if constexpr (EPI == 2) {
    static_assert(WR == 1 && BM == 64, "softmax epilogue needs full-M wave");
    #pragma unroll
    for (int i = 0; i < MR; i++)
      #pragma unroll
      for (int j = 0; j < NR; j++)
        #pragma unroll
        for (int q = 0; q < 4; q++) acc[i][j][q] *= alpha;
    float inv[NR];
    #pragma unroll
    for (int j = 0; j < NR; j++) {
      float mx = -1e30f;
      #pragma unroll
      for (int i = 0; i < MR; i++)
        #pragma unroll
        for (int q = 0; q < 4; q++) mx = fmaxf(mx, acc[i][j][q]);
      mx = fmaxf(mx, __shfl_xor(mx, 16, 64));
      mx = fmaxf(mx, __shfl_xor(mx, 32, 64));
      float sm = 0.f;
      #pragma unroll
      for (int i = 0; i < MR; i++)
        #pragma unroll
        for (int q = 0; q < 4; q++) {
          float e = __expf(acc[i][j][q] - mx);
          acc[i][j][q] = e;
          sm += e;
        }
      sm += __shfl_xor(sm, 16, 64);
      sm += __shfl_xor(sm, 32, 64);
      inv[j] = 1.f / sm;
    }
    float rp[MR][4];
    #pragma unroll
    for (int i = 0; i < MR; i++)
      #pragma unroll
      for (int q = 0; q < 4; q++) rp[i][q] = 0.f;
    unsigned short* Cs = (unsigned short*)C;
    #pragma unroll
    for (int i = 0; i < MR; i++)
      #pragma unroll
      for (int j = 0; j < NR; j++)
        #pragma unroll
        for (int q = 0; q < 4; q++) {
          float a = acc[i][j][q] * inv[j];
          rp[i][q] += a;
          Cs[(long)(i * 16 + fq * 4 + q) * N + tileN + wc * WSN + j * 16 + fr] = f2bf(a);
        }
    #pragma unroll
    for (int off = 1; off <= 8; off <<= 1)
      #pragma unroll
      for (int i = 0; i < MR; i++)
        #pragma unroll
        for (int q = 0; q < 4; q++) rp[i][q] += __shfl_xor(rp[i][q], off, 64);
    if (fr == 0) {
      const int rld = gridDim.x * WC;
      #pragma unroll
      for (int i = 0; i < MR; i++)
        #pragma unroll
        for (int q = 0; q < 4; q++)
          rs_part[((long)zb * 64 + i * 16 + fq * 4 + q) * rld + blockIdx.x * WC + wc] = rp[i][q];
    }
    return;
  }

  #pragma unroll
  for (int i = 0; i < MR; i++) {
    const int mbase = tileM + wr * WSM + i * 16 + fq * 4;
    #pragma unroll
    for (int j = 0; j < NR; j++) {
      const int n = tileN + wc * WSN + j * 16 + fr;
      if constexpr (EPI == 3) {
        #pragma unroll
        for (int q = 0; q < 4; q++) {
          float v = acc[i][j][q] * rowinv_s[mbase + q];
          ((unsigned short*)C)[(long)(mbase + q) * N + n] = f2bf(v);
        }
      } else {
        const float bv = bp ? bp[n] : 0.f;
        #pragma unroll
        for (int q = 0; q < 4; q++) {
          float v = acc[i][j][q] * alpha + bv;
          if constexpr (sizeof(CT) == 2)
            C[(long)(mbase + q) * N + n] = f2bf(v);
          else
            C[(long)(mbase + q) * N + n] = v;
        }
      }
    }
  }
}

// ---- GRU combine + fused rmsnorm of the new slots (block = one row) ----
__global__ __launch_bounds__(256) void gru_k(const float* __restrict__ gi,
                                             const float* __restrict__ gh,
                                             const float* __restrict__ h,
                                             const float* __restrict__ snw,
                                             float* __restrict__ out,
                                             unsigned short* __restrict__ out_bf,
                                             unsigned short* __restrict__ sn_out) {
  const int r = blockIdx.x;
  const int tid = threadIdx.x;
  const int c = tid * 4;
  const long gb = (long)r * 3072 + c;
  float4 ir = *(const float4*)(gi + gb);
  float4 iz = *(const float4*)(gi + gb + 1024);
  float4 in = *(const float4*)(gi + gb + 2048);
  float4 hr = *(const float4*)(gh + gb);
  float4 hz = *(const float4*)(gh + gb + 1024);
  float4 hn = *(const float4*)(gh + gb + 2048);
  float4 hv = *(const float4*)(h + (long)r * 1024 + c);
  float4 o;
  { float rr = sigm(ir.x + hr.x), zz = sigm(iz.x + hz.x);
    float nn = tanhf(in.x + rr * hn.x); o.x = (1.f - zz) * nn + zz * hv.x; }
  { float rr = sigm(ir.y + hr.y), zz = sigm(iz.y + hz.y);
    float nn = tanhf(in.y + rr * hn.y); o.y = (1.f - zz) * nn + zz * hv.y; }
  { float rr = sigm(ir.z + hr.z), zz = sigm(iz.z + hz.z);
    float nn = tanhf(in.z + rr * hn.z); o.z = (1.f - zz) * nn + zz * hv.z; }
  { float rr = sigm(ir.w + hr.w), zz = sigm(iz.w + hz.w);
    float nn = tanhf(in.w + rr * hn.w); o.w = (1.f - zz) * nn + zz * hv.w; }
  *(float4*)(out + (long)r * 1024 + c) = o;
  ushort4 ob;
  ob.x = f2bf(o.x); ob.y = f2bf(o.y); ob.z = f2bf(o.z); ob.w = f2bf(o.w);
  *(ushort4*)(out_bf + (long)r * 1024 + c) = ob;
  float ss = o.x * o.x + o.y * o.y + o.z * o.z + o.w * o.w;
  #pragma unroll
  for (int off = 32; off; off >>= 1) ss += __shfl_xor(ss, off, 64);
  __shared__ float sb[4];
  if ((tid & 63) == 0) sb[tid >> 6] = ss;
  __syncthreads();
  const float tot = sb[0] + sb[1] + sb[2] + sb[3];
  const float rs = rsqrtf(tot * (1.0f / 1024.0f) + 1e-6f);
  float4 wv = *(const float4*)(snw + c);
  ushort4 so;
  so.x = f2bf(o.x * rs * wv.x); so.y = f2bf(o.y * rs * wv.y);
  so.z = f2bf(o.z * rs * wv.z); so.w = f2bf(o.w * rs * wv.w);
  *(ushort4*)(sn_out + (long)r * 1024 + c) = so;
}

extern "C" void kernel_launch(void* const* d_in, const int* in_sizes, int n_in,
                              void* d_out, int out_size, void* d_ws, size_t ws_size,
                              hipStream_t stream) {
  const float* slots_in = (const float*)d_in[0];
  const float* P        = (const float*)d_in[1];
  const float* Wq       = (const float*)d_in[2];
  const float* Wk       = (const float*)d_in[3];
  const float* Wv       = (const float*)d_in[4];
  const float* wi       = (const float*)d_in[5];
  const float* wh       = (const float*)d_in[6];
  const float* bi       = (const float*)d_in[7];
  const float* bh       = (const float*)d_in[8];
  const float* snw      = (const float*)d_in[9];
  const float* inw      = (const float*)d_in[10];

  const size_t MB = 1024ull * 1024ull;
  char* ws = (char*)d_ws;
  unsigned short* kproj = (unsigned short*)(ws + 0);        // 64MB [b][m][e] bf16
  unsigned short* vt    = (unsigned short*)(ws + 64 * MB);  // 64MB [b][e][m] bf16
  char* S               = ws + 128 * MB;                    // 64MB reuse region
  unsigned short* Pn    = (unsigned short*)(S);             // prologue only (64MB)
  unsigned short* sn    = (unsigned short*)(S);             // 1MB
  unsigned short* qb    = (unsigned short*)(S + 1 * MB);    // 1MB
  unsigned short* attnb = (unsigned short*)(S + 2 * MB);    // 4MB
  unsigned short* updb  = (unsigned short*)(S + 6 * MB);    // 1MB
  unsigned short* slotsb= (unsigned short*)(S + 7 * MB);    // 1MB (adjacent to updb!)
  float* gi             = (float*)(S + 8 * MB);             // 6MB
  float* gh             = (float*)(S + 14 * MB);            // 6MB (adjacent to gi!)
  float* rs_part        = (float*)(S + 28 * MB);            // 256KB
  unsigned short* wq_b  = (unsigned short*)(S + 30 * MB);   // 2MB
  unsigned short* wi_b  = (unsigned short*)(S + 32 * MB);   // 6MB
  unsigned short* wh_b  = (unsigned short*)(S + 38 * MB);   // 6MB (adjacent to wi_b!)
  unsigned short* wk_b  = (unsigned short*)(ws + 192 * MB); // 2MB  } combined W [2048][1024]
  unsigned short* wv_b  = (unsigned short*)(ws + 194 * MB); // 2MB  }
  float* slots          = (float*)(ws + 196 * MB);          // 2MB

  auto cvt = [&](const float* in, unsigned short* out, long n) {
    long n8 = n / 8;
    cvt_bf16_k<<<dim3((unsigned)((n8 + 255) / 256)), 256, 0, stream>>>(in, out, n8);
  };

  // ---- prologue ----
  cvt(Wk, wk_b, 1024L * 1024);
  cvt(Wv, wv_b, 1024L * 1024);
  rmsnorm_k<<<32768, 256, 0, stream>>>(P, inw, Pn, nullptr);
  // combined K+V projection: M=32768, N=2048, K=1024 (8-phase 256^2)
  proj_k<<<1024, 512, 0, stream>>>(Pn, wk_b, kproj, vt);
  cvt(Wq, wq_b, 1024L * 1024);
  cvt(wi, wi_b, 3072L * 1024);
  cvt(wh, wh_b, 3072L * 1024);
  // fused: sn = rmsnorm(slots_in), slotsb = bf16(slots_in)
  rmsnorm_k<<<512, 256, 0, stream>>>(slots_in, snw, sn, slotsb);

  // ---- 3 iterations (5 dispatches each) ----
  for (int it = 0; it < 3; ++it) {
    // q = sn @ Wq^T : M=512, N=1024, K=1024  (256 blocks)
    gemm_bt<64, 32, 2, 2, unsigned short, 0, 1>
        <<<dim3(32, 8, 1), 256, 0, stream>>>(sn, wq_b, qb, 1024, 1024, 1024, 1024,
                                             0, 0, 0, nullptr, nullptr, 1.f, nullptr);
    // attn[b][k][m] = softmax_k((q_b @ kproj_b^T)/32) + row partials (256 blocks)
    gemm_bt<64, 128, 1, 4, unsigned short, 2, 1>
        <<<dim3(32, 1, 8), 256, 0, stream>>>(qb, kproj, attnb, 4096, 1024, 1024, 1024,
                                             64L * 1024, 4096L * 1024, 64L * 4096,
                                             nullptr, nullptr, 0.03125f, rs_part);
    // updates = (attn_b @ vt_b^T) * rowinv : K=4096 unsplit, EPI=3 (256 blocks)
    gemm_bt<64, 32, 2, 2, unsigned short, 3, 1>
        <<<dim3(32, 1, 8), 256, 0, stream>>>(attnb, vt, updb, 1024, 4096, 4096, 4096,
                                             64L * 4096, 4096L * 1024, 64L * 1024,
                                             nullptr, nullptr, 1.f, rs_part);
    // merged gi/gh: z=0 -> gi = updb@wi^T+bi, z=1 -> gh = slotsb@wh^T+bh
    gemm_bt<64, 64, 2, 2, float, 0, 1>
        <<<dim3(48, 8, 2), 256, 0, stream>>>(updb, wi_b, gi, 3072, 1024, 1024, 1024,
                                             524288, 3145728, 1572864, bi, bh, 1.f, nullptr);
    const float* hsrc = (it == 0) ? slots_in : slots;
    float* dst = (it == 2) ? (float*)d_out : slots;
    gru_k<<<512, 256, 0, stream>>>(gi, gh, hsrc, snw, dst, slotsb, sn);
  }
}

// Round 8
// 441.971 us; speedup vs baseline: 1.1158x; 1.1158x over previous
//
#include <hip/hip_runtime.h>

typedef __attribute__((ext_vector_type(4))) float f32x4;
typedef __attribute__((ext_vector_type(8))) short s16x8;

static __device__ __forceinline__ unsigned short f2bf(float f) {
  unsigned int u = __builtin_bit_cast(unsigned int, f);
  u += 0x7fffu + ((u >> 16) & 1u);
  return (unsigned short)(u >> 16);
}
static __device__ __forceinline__ float sigm(float x) { return 1.0f / (1.0f + __expf(-x)); }

// async global->LDS, 16B per lane. LDS dest = wave-uniform base + lane*16.
static __device__ __forceinline__ void gload16(const unsigned short* g, unsigned short* l) {
  __builtin_amdgcn_global_load_lds(
      (const __attribute__((address_space(1))) void*)g,
      (__attribute__((address_space(3))) void*)l, 16, 0, 0);
}

#define FENCE() asm volatile("" ::: "memory")
#define BAR()   { FENCE(); __builtin_amdgcn_s_barrier(); FENCE(); }
#define LGKM0() asm volatile("s_waitcnt lgkmcnt(0)" ::: "memory")

// ================= 8-phase 256^2 projection kernel (round-4 schedule, best measured) =================
// C_full[32768][2048] = A[32768][1024] @ W[2048][1024]^T, epilogue splits:
//   n<1024  -> kproj[b][m][n]; n>=1024 -> vt[b][n-1024][m] (transposed)
__global__ __launch_bounds__(512, 2) void proj_k(
    const unsigned short* __restrict__ A, const unsigned short* __restrict__ W,
    unsigned short* __restrict__ kproj, unsigned short* __restrict__ vt) {
  __shared__ unsigned short lds[2][2][2][8192];  // [buf][A/B][half][128*64]
  const int tid = threadIdx.x, lane = tid & 63, wid = tid >> 6;
  const int wm = wid >> 2, wn = wid & 3;
  // bijective XCD swizzle (nwg = 1024 = 8*128)
  const int wg = ((int)blockIdx.x & 7) * 128 + ((int)blockIdx.x >> 3);
  const int mt = wg >> 3, nt = wg & 7;
  const unsigned short* Ap = A + (long)mt * 256 * 1024;
  const unsigned short* Wp = W + (long)nt * 256 * 1024;
  const int srow = lane >> 3;                       // 0..7
  const int scol = (((lane & 7) ^ srow) << 3);      // pre-swizzled short col
  const int fr = lane & 15, fq = lane >> 4;
  const int xorv = (fr & 7) << 3;                   // read-side XOR (shorts)

#define STAGE(buf, T, h, t)                                                    \
  { const unsigned short* gp_ = (T) ? Wp : Ap;                                 \
    _Pragma("unroll") for (int p = 0; p < 2; p++) {                            \
      int r_ = wid * 16 + p * 8 + srow;                                        \
      gload16(gp_ + (long)((h) * 128 + r_) * 1024 + (long)(t) * 64 + scol,     \
              &lds[buf][T][h][(wid * 2 + p) * 512]);                           \
    } }

#define LDA_FRAG(aq)                                                           \
  { _Pragma("unroll") for (int i = 0; i < 4; i++)                              \
      _Pragma("unroll") for (int kk = 0; kk < 2; kk++)                         \
        af[i * 2 + kk] = *(const s16x8*)(Ab + ((aq) * 64 + i * 16 + fr) * 64 + \
                                         ((kk * 32 + fq * 8) ^ xorv)); }

#define LDB_FRAG(bq, arr)                                                      \
  { _Pragma("unroll") for (int j = 0; j < 2; j++)                              \
      _Pragma("unroll") for (int kk = 0; kk < 2; kk++)                         \
        arr[j * 2 + kk] = *(const s16x8*)(Bb + ((wn & 1) * 64 + ((bq) * 2 + j) * 16 + fr) * 64 + \
                                          ((kk * 32 + fq * 8) ^ xorv)); }

#define MM_Q(aq, bq, arr)                                                      \
  { __builtin_amdgcn_s_setprio(1);                                             \
    _Pragma("unroll") for (int i = 0; i < 4; i++)                              \
      _Pragma("unroll") for (int j = 0; j < 2; j++)                            \
        _Pragma("unroll") for (int kk = 0; kk < 2; kk++)                       \
          acc[(aq) * 4 + i][(bq) * 2 + j] = __builtin_amdgcn_mfma_f32_16x16x32_bf16( \
              af[i * 2 + kk], arr[j * 2 + kk], acc[(aq) * 4 + i][(bq) * 2 + j], 0, 0, 0); \
    __builtin_amdgcn_s_setprio(0); }

  f32x4 acc[8][4];
  #pragma unroll
  for (int i = 0; i < 8; i++)
    #pragma unroll
    for (int j = 0; j < 4; j++) acc[i][j] = (f32x4){0.f, 0.f, 0.f, 0.f};

  // prologue: tile0 A0,A1,B0,B1 + tile1 B0,B1
  STAGE(0, 0, 0, 0); STAGE(0, 0, 1, 0); STAGE(0, 1, 0, 0); STAGE(0, 1, 1, 0);
  STAGE(1, 1, 0, 1); STAGE(1, 1, 1, 1);
  asm volatile("s_waitcnt vmcnt(4)" ::: "memory");
  BAR();

  s16x8 af[8], b0f[4], b1f[4];
  for (int t = 0; t < 16; ++t) {
    const int pt = t & 1;
    const unsigned short* Ab = &lds[pt][0][wm][0];
    const unsigned short* Bb = &lds[pt][1][wn >> 1][0];
    // ---- phase 1: quadrant (0,0); stage A0(t+1) ----
    LDA_FRAG(0); LDB_FRAG(0, b0f);
    if (t < 15) STAGE(pt ^ 1, 0, 0, t + 1);
    BAR(); LGKM0();
    MM_Q(0, 0, b0f);
    BAR();
    // ---- phase 2: quadrant (0,1); stage A1(t+1) ----
    LDB_FRAG(1, b1f);
    if (t < 15) STAGE(pt ^ 1, 0, 1, t + 1);
    BAR(); LGKM0();
    MM_Q(0, 1, b1f);
    BAR();
    // ---- phase 3: quadrant (1,0); stage B0(t+2) ----
    LDA_FRAG(1);
    if (t < 14) STAGE(pt, 1, 0, t + 2);
    BAR(); LGKM0();
    MM_Q(1, 0, b0f);
    BAR();
    // ---- phase 4: quadrant (1,1); stage B1(t+2); counted vmcnt ----
    if (t < 14) STAGE(pt, 1, 1, t + 2);
    if (t == 14) { asm volatile("s_waitcnt vmcnt(0)" ::: "memory"); }
    else         { asm volatile("s_waitcnt vmcnt(4)" ::: "memory"); }
    BAR();
    MM_Q(1, 1, b1f);
    BAR();
  }

  // ---- epilogue: split K/V store ----
  const int nbase = nt * 256 + wn * 64;
  const bool kside = (nbase < 1024);
  #pragma unroll
  for (int i = 0; i < 8; i++) {
    const int gm0 = mt * 256 + wm * 128 + i * 16 + fq * 4;
    const int b = gm0 >> 12, mrow = gm0 & 4095;
    #pragma unroll
    for (int j = 0; j < 4; j++) {
      const int n = nbase + j * 16 + fr;
      if (kside) {
        unsigned short* dst = kproj + ((long)b * 4096 + mrow) * 1024 + n;
        #pragma unroll
        for (int q = 0; q < 4; q++) dst[(long)q * 1024] = f2bf(acc[i][j][q]);
      } else {
        ushort4 o;
        o.x = f2bf(acc[i][j][0]); o.y = f2bf(acc[i][j][1]);
        o.z = f2bf(acc[i][j][2]); o.w = f2bf(acc[i][j][3]);
        *(ushort4*)(vt + ((long)b * 1024 + (n - 1024)) * 4096 + mrow) = o;
      }
    }
  }
#undef STAGE
#undef LDA_FRAG
#undef LDB_FRAG
#undef MM_Q
}

// ---------------- rmsnorm rows of length 1024: fp32 -> bf16 (+optional raw bf16) ----------------
__global__ __launch_bounds__(256) void rmsnorm_k(const float* __restrict__ x,
                                                 const float* __restrict__ w,
                                                 unsigned short* __restrict__ y,
                                                 unsigned short* __restrict__ y_raw) {
  const int row = blockIdx.x;
  const int tid = threadIdx.x;
  const float4* xp = (const float4*)(x + (long)row * 1024);
  float4 v = xp[tid];
  float ss = v.x * v.x + v.y * v.y + v.z * v.z + v.w * v.w;
  #pragma unroll
  for (int off = 32; off; off >>= 1) ss += __shfl_xor(ss, off, 64);
  __shared__ float sb[4];
  if ((tid & 63) == 0) sb[tid >> 6] = ss;
  __syncthreads();
  float tot = sb[0] + sb[1] + sb[2] + sb[3];
  float rs = rsqrtf(tot * (1.0f / 1024.0f) + 1e-6f);
  const float4* wp = (const float4*)w;
  float4 wv = wp[tid];
  ushort4 o;
  o.x = f2bf(v.x * rs * wv.x);
  o.y = f2bf(v.y * rs * wv.y);
  o.z = f2bf(v.z * rs * wv.z);
  o.w = f2bf(v.w * rs * wv.w);
  ((ushort4*)y)[(long)row * 256 + tid] = o;
  if (y_raw) {
    ushort4 r;
    r.x = f2bf(v.x); r.y = f2bf(v.y); r.z = f2bf(v.z); r.w = f2bf(v.w);
    ((ushort4*)y_raw)[(long)row * 256 + tid] = r;
  }
}

// ---------------- fp32 -> bf16 convert (8 elems/thread) ----------------
__global__ __launch_bounds__(256) void cvt_bf16_k(const float* __restrict__ in,
                                                  unsigned short* __restrict__ out,
                                                  long n8) {
  long i = (long)blockIdx.x * 256 + threadIdx.x;
  if (i >= n8) return;
  const float4* p = (const float4*)in;
  float4 a = p[i * 2], b = p[i * 2 + 1];
  ushort4 lo, hi;
  lo.x = f2bf(a.x); lo.y = f2bf(a.y); lo.z = f2bf(a.z); lo.w = f2bf(a.w);
  hi.x = f2bf(b.x); hi.y = f2bf(b.y); hi.z = f2bf(b.z); hi.w = f2bf(b.w);
  ushort4* o = (ushort4*)out;
  o[i * 2] = lo;
  o[i * 2 + 1] = hi;
}

// ---------------- GEMM: C = alpha * A[M][K] @ W[N][K]^T (+bias) ----------------
// EPI: 0 = plain store; 2 = softmax over M(=64) -> bf16 attn + row partials.
// SPLIT: K-split batching. bias2: used for odd blockIdx.z (merged gi/gh).
template <int BM, int BN, int WR, int WC, typename CT, int EPI, int SPLIT>
__global__ __launch_bounds__(WR * WC * 64) void gemm_bt(
    const unsigned short* __restrict__ A, const unsigned short* __restrict__ W,
    CT* __restrict__ C, int N, int Klen, int lda, int ldw,
    long sA, long sW, long sC, const float* __restrict__ bias,
    const float* __restrict__ bias2, float alpha, float* __restrict__ rs_part) {
  constexpr int BK = 64;
  constexpr int NT = WR * WC * 64;
  static_assert(NT == 256, "256 threads");
  constexpr int WSM = BM / WR, WSN = BN / WC;
  constexpr int MR = WSM / 16, NR = WSN / 16;
  constexpr int SEG_A = BM / 8, SEG_W = BN / 8;
  constexpr int PA = SEG_A / 4, PW = SEG_W / 4;
  static_assert(SEG_A % 4 == 0 && SEG_W % 4 == 0, "seg divisibility");
  __shared__ unsigned short As[BM * BK];
  __shared__ unsigned short Ws[BN * BK];
  const int tid = threadIdx.x, lane = tid & 63, wid = tid >> 6;
  const int wr = wid / WC, wc = wid % WC;
  const int tileN = blockIdx.x * BN, tileM = blockIdx.y * BM;
  const int zb = blockIdx.z / SPLIT, zs = blockIdx.z % SPLIT;
  A += (long)zb * sA + (long)zs * Klen;
  W += (long)zb * sW + (long)zs * Klen;
  C += (long)blockIdx.z * sC;
  const float* bp = (bias2 && (blockIdx.z & 1)) ? bias2 : bias;
  const int srow = lane >> 3;
  const int scol = (lane & 7) * 8;
  f32x4 acc[MR][NR];
  #pragma unroll
  for (int i = 0; i < MR; i++)
    #pragma unroll
    for (int j = 0; j < NR; j++) acc[i][j] = (f32x4){0.f, 0.f, 0.f, 0.f};
  const int fr = lane & 15, fq = lane >> 4;

  for (int k0 = 0; k0 < Klen; k0 += BK) {
    #pragma unroll
    for (int p = 0; p < PA; p++) {
      int seg = wid * PA + p;
      gload16(A + (long)(tileM + seg * 8 + srow) * lda + k0 + scol, &As[seg * 512]);
    }
    #pragma unroll
    for (int p = 0; p < PW; p++) {
      int seg = wid * PW + p;
      gload16(W + (long)(tileN + seg * 8 + srow) * ldw + k0 + scol, &Ws[seg * 512]);
    }
    __syncthreads();
    #pragma unroll
    for (int kk = 0; kk < BK; kk += 32) {
      s16x8 af[MR], bf[NR];
      #pragma unroll
      for (int i = 0; i < MR; i++)
        af[i] = *(const s16x8*)(&As[(wr * WSM + i * 16 + fr) * BK + kk + fq * 8]);
      #pragma unroll
      for (int j = 0; j < NR; j++)
        bf[j] = *(const s16x8*)(&Ws[(wc * WSN + j * 16 + fr) * BK + kk + fq * 8]);
      #pragma unroll
      for (int i = 0; i < MR; i++)
        #pragma unroll
        for (int j = 0; j < NR; j++)
          acc[i][j] = __builtin_amdgcn_mfma_f32_16x16x32_bf16(af[i], bf[j], acc[i][j], 0, 0, 0);
    }
    __syncthreads();
  }

  if constexpr (EPI == 2) {
    static_assert(WR == 1 && BM == 64, "softmax epilogue needs full-M wave");
    #pragma unroll
    for (int i = 0; i < MR; i++)
      #pragma unroll
      for (int j = 0; j < NR; j++)
        #pragma unroll
        for (int q = 0; q < 4; q++) acc[i][j][q] *= alpha;
    float inv[NR];
    #pragma unroll
    for (int j = 0; j < NR; j++) {
      float mx = -1e30f;
      #pragma unroll
      for (int i = 0; i < MR; i++)
        #pragma unroll
        for (int q = 0; q < 4; q++) mx = fmaxf(mx, acc[i][j][q]);
      mx = fmaxf(mx, __shfl_xor(mx, 16, 64));
      mx = fmaxf(mx, __shfl_xor(mx, 32, 64));
      float sm = 0.f;
      #pragma unroll
      for (int i = 0; i < MR; i++)
        #pragma unroll
        for (int q = 0; q < 4; q++) {
          float e = __expf(acc[i][j][q] - mx);
          acc[i][j][q] = e;
          sm += e;
        }
      sm += __shfl_xor(sm, 16, 64);
      sm += __shfl_xor(sm, 32, 64);
      inv[j] = 1.f / sm;
    }
    float rp[MR][4];
    #pragma unroll
    for (int i = 0; i < MR; i++)
      #pragma unroll
      for (int q = 0; q < 4; q++) rp[i][q] = 0.f;
    unsigned short* Cs = (unsigned short*)C;
    #pragma unroll
    for (int i = 0; i < MR; i++)
      #pragma unroll
      for (int j = 0; j < NR; j++)
        #pragma unroll
        for (int q = 0; q < 4; q++) {
          float a = acc[i][j][q] * inv[j];
          rp[i][q] += a;
          Cs[(long)(i * 16 + fq * 4 + q) * N + tileN + wc * WSN + j * 16 + fr] = f2bf(a);
        }
    #pragma unroll
    for (int off = 1; off <= 8; off <<= 1)
      #pragma unroll
      for (int i = 0; i < MR; i++)
        #pragma unroll
        for (int q = 0; q < 4; q++) rp[i][q] += __shfl_xor(rp[i][q], off, 64);
    if (fr == 0) {
      const int rld = gridDim.x * WC;
      #pragma unroll
      for (int i = 0; i < MR; i++)
        #pragma unroll
        for (int q = 0; q < 4; q++)
          rs_part[((long)zb * 64 + i * 16 + fq * 4 + q) * rld + blockIdx.x * WC + wc] = rp[i][q];
    }
    return;
  }

  #pragma unroll
  for (int i = 0; i < MR; i++) {
    const int mbase = tileM + wr * WSM + i * 16 + fq * 4;
    #pragma unroll
    for (int j = 0; j < NR; j++) {
      const int n = tileN + wc * WSN + j * 16 + fr;
      const float bv = bp ? bp[n] : 0.f;
      #pragma unroll
      for (int q = 0; q < 4; q++) {
        float v = acc[i][j][q] * alpha + bv;
        if constexpr (sizeof(CT) == 2)
          C[(long)(mbase + q) * N + n] = f2bf(v);
        else
          C[(long)(mbase + q) * N + n] = v;
      }
    }
  }
}

// ---- reduce 8 K-splits; in-block rowsum of rs_part -> rowinv; scale; cast bf16 ----
// block = one (b,k) row (512 blocks x 256 threads, 4 elems/thread)
__global__ __launch_bounds__(256) void upd_reduce_k(const float* __restrict__ part,
                                                    const float* __restrict__ rs_part,
                                                    unsigned short* __restrict__ out) {
  const int row = blockIdx.x;  // b*64 + k
  const int tid = threadIdx.x;
  float s = (tid < 128) ? rs_part[(long)row * 128 + tid] : 0.f;
  #pragma unroll
  for (int off = 32; off; off >>= 1) s += __shfl_xor(s, off, 64);
  __shared__ float sb[4];
  if ((tid & 63) == 0) sb[tid >> 6] = s;
  __syncthreads();
  const float inv = 1.f / (sb[0] + sb[1] + sb[2] + sb[3] + 1e-6f);
  const float* base = part + (long)(row >> 6) * 8 * 65536 + (long)(row & 63) * 1024 + tid * 4;
  float4 acc4 = {0.f, 0.f, 0.f, 0.f};
  #pragma unroll
  for (int sp = 0; sp < 8; sp++) {
    float4 v = *(const float4*)(base + (long)sp * 65536);
    acc4.x += v.x; acc4.y += v.y; acc4.z += v.z; acc4.w += v.w;
  }
  ushort4 o;
  o.x = f2bf(acc4.x * inv); o.y = f2bf(acc4.y * inv);
  o.z = f2bf(acc4.z * inv); o.w = f2bf(acc4.w * inv);
  ((ushort4*)out)[(long)row * 256 + tid] = o;
}

// ---- GRU combine + fused rmsnorm of the new slots (block = one row) ----
__global__ __launch_bounds__(256) void gru_k(const float* __restrict__ gi,
                                             const float* __restrict__ gh,
                                             const float* __restrict__ h,
                                             const float* __restrict__ snw,
                                             float* __restrict__ out,
                                             unsigned short* __restrict__ out_bf,
                                             unsigned short* __restrict__ sn_out) {
  const int r = blockIdx.x;
  const int tid = threadIdx.x;
  const int c = tid * 4;
  const long gb = (long)r * 3072 + c;
  float4 ir = *(const float4*)(gi + gb);
  float4 iz = *(const float4*)(gi + gb + 1024);
  float4 in = *(const float4*)(gi + gb + 2048);
  float4 hr = *(const float4*)(gh + gb);
  float4 hz = *(const float4*)(gh + gb + 1024);
  float4 hn = *(const float4*)(gh + gb + 2048);
  float4 hv = *(const float4*)(h + (long)r * 1024 + c);
  float4 o;
  { float rr = sigm(ir.x + hr.x), zz = sigm(iz.x + hz.x);
    float nn = tanhf(in.x + rr * hn.x); o.x = (1.f - zz) * nn + zz * hv.x; }
  { float rr = sigm(ir.y + hr.y), zz = sigm(iz.y + hz.y);
    float nn = tanhf(in.y + rr * hn.y); o.y = (1.f - zz) * nn + zz * hv.y; }
  { float rr = sigm(ir.z + hr.z), zz = sigm(iz.z + hz.z);
    float nn = tanhf(in.z + rr * hn.z); o.z = (1.f - zz) * nn + zz * hv.z; }
  { float rr = sigm(ir.w + hr.w), zz = sigm(iz.w + hz.w);
    float nn = tanhf(in.w + rr * hn.w); o.w = (1.f - zz) * nn + zz * hv.w; }
  *(float4*)(out + (long)r * 1024 + c) = o;
  ushort4 ob;
  ob.x = f2bf(o.x); ob.y = f2bf(o.y); ob.z = f2bf(o.z); ob.w = f2bf(o.w);
  *(ushort4*)(out_bf + (long)r * 1024 + c) = ob;
  float ss = o.x * o.x + o.y * o.y + o.z * o.z + o.w * o.w;
  #pragma unroll
  for (int off = 32; off; off >>= 1) ss += __shfl_xor(ss, off, 64);
  __shared__ float sb[4];
  if ((tid & 63) == 0) sb[tid >> 6] = ss;
  __syncthreads();
  const float tot = sb[0] + sb[1] + sb[2] + sb[3];
  const float rs = rsqrtf(tot * (1.0f / 1024.0f) + 1e-6f);
  float4 wv = *(const float4*)(snw + c);
  ushort4 so;
  so.x = f2bf(o.x * rs * wv.x); so.y = f2bf(o.y * rs * wv.y);
  so.z = f2bf(o.z * rs * wv.z); so.w = f2bf(o.w * rs * wv.w);
  *(ushort4*)(sn_out + (long)r * 1024 + c) = so;
}

extern "C" void kernel_launch(void* const* d_in, const int* in_sizes, int n_in,
                              void* d_out, int out_size, void* d_ws, size_t ws_size,
                              hipStream_t stream) {
  const float* slots_in = (const float*)d_in[0];
  const float* P        = (const float*)d_in[1];
  const float* Wq       = (const float*)d_in[2];
  const float* Wk       = (const float*)d_in[3];
  const float* Wv       = (const float*)d_in[4];
  const float* wi       = (const float*)d_in[5];
  const float* wh       = (const float*)d_in[6];
  const float* bi       = (const float*)d_in[7];
  const float* bh       = (const float*)d_in[8];
  const float* snw      = (const float*)d_in[9];
  const float* inw      = (const float*)d_in[10];

  const size_t MB = 1024ull * 1024ull;
  char* ws = (char*)d_ws;
  unsigned short* kproj = (unsigned short*)(ws + 0);        // 64MB [b][m][e] bf16
  unsigned short* vt    = (unsigned short*)(ws + 64 * MB);  // 64MB [b][e][m] bf16
  char* S               = ws + 128 * MB;                    // 64MB reuse region
  unsigned short* Pn    = (unsigned short*)(S);             // prologue only (64MB)
  unsigned short* sn    = (unsigned short*)(S);             // 1MB
  unsigned short* qb    = (unsigned short*)(S + 1 * MB);    // 1MB
  unsigned short* attnb = (unsigned short*)(S + 2 * MB);    // 4MB
  unsigned short* updb  = (unsigned short*)(S + 6 * MB);    // 1MB
  unsigned short* slotsb= (unsigned short*)(S + 7 * MB);    // 1MB (adjacent to updb!)
  float* gi             = (float*)(S + 8 * MB);             // 6MB
  float* gh             = (float*)(S + 14 * MB);            // 6MB (adjacent to gi!)
  float* Cpart          = (float*)(S + 20 * MB);            // 16MB [b*8+s][64][1024]
  float* rs_part        = (float*)(S + 36 * MB);            // 256KB
  unsigned short* wq_b  = (unsigned short*)(S + 37 * MB);   // 2MB
  unsigned short* wi_b  = (unsigned short*)(S + 39 * MB);   // 6MB
  unsigned short* wh_b  = (unsigned short*)(S + 45 * MB);   // 6MB (adjacent to wi_b!)
  unsigned short* wk_b  = (unsigned short*)(ws + 192 * MB); // 2MB  } combined W [2048][1024]
  unsigned short* wv_b  = (unsigned short*)(ws + 194 * MB); // 2MB  }
  float* slots          = (float*)(ws + 196 * MB);          // 2MB

  auto cvt = [&](const float* in, unsigned short* out, long n) {
    long n8 = n / 8;
    cvt_bf16_k<<<dim3((unsigned)((n8 + 255) / 256)), 256, 0, stream>>>(in, out, n8);
  };

  // ---- prologue ----
  cvt(Wk, wk_b, 1024L * 1024);
  cvt(Wv, wv_b, 1024L * 1024);
  rmsnorm_k<<<32768, 256, 0, stream>>>(P, inw, Pn, nullptr);
  // combined K+V projection: M=32768, N=2048, K=1024 (8-phase 256^2)
  proj_k<<<1024, 512, 0, stream>>>(Pn, wk_b, kproj, vt);
  cvt(Wq, wq_b, 1024L * 1024);
  cvt(wi, wi_b, 3072L * 1024);
  cvt(wh, wh_b, 3072L * 1024);
  // fused: sn = rmsnorm(slots_in), slotsb = bf16(slots_in)
  rmsnorm_k<<<512, 256, 0, stream>>>(slots_in, snw, sn, slotsb);

  // ---- 3 iterations (6 dispatches each) ----
  for (int it = 0; it < 3; ++it) {
    // q = sn @ Wq^T : M=512, N=1024, K=1024
    gemm_bt<64, 64, 2, 2, unsigned short, 0, 1>
        <<<dim3(16, 8, 1), 256, 0, stream>>>(sn, wq_b, qb, 1024, 1024, 1024, 1024,
                                             0, 0, 0, nullptr, nullptr, 1.f, nullptr);
    // attn[b][k][m] = softmax_k((q_b @ kproj_b^T)/32) + row partials
    gemm_bt<64, 128, 1, 4, unsigned short, 2, 1>
        <<<dim3(32, 1, 8), 256, 0, stream>>>(qb, kproj, attnb, 4096, 1024, 1024, 1024,
                                             64L * 1024, 4096L * 1024, 64L * 4096,
                                             nullptr, nullptr, 0.03125f, rs_part);
    // updates partials: attn_b @ vt_b^T, K=4096 split 8x512 (1024 blocks, 4/CU)
    gemm_bt<64, 64, 2, 2, float, 0, 8>
        <<<dim3(16, 1, 64), 256, 0, stream>>>(attnb, vt, Cpart, 1024, 512, 4096, 4096,
                                              64L * 4096, 1024L * 4096, 64L * 1024,
                                              nullptr, nullptr, 1.f, nullptr);
    upd_reduce_k<<<512, 256, 0, stream>>>(Cpart, rs_part, updb);
    // merged gi/gh: z=0 -> gi = updb@wi^T+bi, z=1 -> gh = slotsb@wh^T+bh
    gemm_bt<64, 64, 2, 2, float, 0, 1>
        <<<dim3(48, 8, 2), 256, 0, stream>>>(updb, wi_b, gi, 3072, 1024, 1024, 1024,
                                             524288, 3145728, 1572864, bi, bh, 1.f, nullptr);
    const float* hsrc = (it == 0) ? slots_in : slots;
    float* dst = (it == 2) ? (float*)d_out : slots;
    gru_k<<<512, 256, 0, stream>>>(gi, gh, hsrc, snw, dst, slotsb, sn);
  }
}

// Round 9
// 432.792 us; speedup vs baseline: 1.1395x; 1.0212x over previous
//
#include <hip/hip_runtime.h>

typedef __attribute__((ext_vector_type(4))) float f32x4;
typedef __attribute__((ext_vector_type(8))) short s16x8;

static __device__ __forceinline__ unsigned short f2bf(float f) {
  unsigned int u = __builtin_bit_cast(unsigned int, f);
  u += 0x7fffu + ((u >> 16) & 1u);
  return (unsigned short)(u >> 16);
}
static __device__ __forceinline__ float bf2f(unsigned short u) {
  return __builtin_bit_cast(float, (unsigned int)u << 16);
}
static __device__ __forceinline__ float sigm(float x) { return 1.0f / (1.0f + __expf(-x)); }

// async global->LDS, 16B per lane. LDS dest = wave-uniform base + lane*16.
static __device__ __forceinline__ void gload16(const unsigned short* g, unsigned short* l) {
  __builtin_amdgcn_global_load_lds(
      (const __attribute__((address_space(1))) void*)g,
      (__attribute__((address_space(3))) void*)l, 16, 0, 0);
}

#define FENCE() asm volatile("" ::: "memory")
#define BAR()   { FENCE(); __builtin_amdgcn_s_barrier(); FENCE(); }
#define LGKM0() asm volatile("s_waitcnt lgkmcnt(0)" ::: "memory")

// ================= 8-phase 256^2 projection kernel (round-4 schedule, best measured) =================
// C_full[32768][2048] = A[32768][1024] @ W[2048][1024]^T, epilogue splits:
//   n<1024  -> kproj[b][m][n]; n>=1024 -> vt[b][n-1024][m] (transposed)
__global__ __launch_bounds__(512, 2) void proj_k(
    const unsigned short* __restrict__ A, const unsigned short* __restrict__ W,
    unsigned short* __restrict__ kproj, unsigned short* __restrict__ vt) {
  __shared__ unsigned short lds[2][2][2][8192];  // [buf][A/B][half][128*64]
  const int tid = threadIdx.x, lane = tid & 63, wid = tid >> 6;
  const int wm = wid >> 2, wn = wid & 3;
  // bijective XCD swizzle (nwg = 1024 = 8*128)
  const int wg = ((int)blockIdx.x & 7) * 128 + ((int)blockIdx.x >> 3);
  const int mt = wg >> 3, nt = wg & 7;
  const unsigned short* Ap = A + (long)mt * 256 * 1024;
  const unsigned short* Wp = W + (long)nt * 256 * 1024;
  const int srow = lane >> 3;                       // 0..7
  const int scol = (((lane & 7) ^ srow) << 3);      // pre-swizzled short col
  const int fr = lane & 15, fq = lane >> 4;
  const int xorv = (fr & 7) << 3;                   // read-side XOR (shorts)

#define STAGE(buf, T, h, t)                                                    \
  { const unsigned short* gp_ = (T) ? Wp : Ap;                                 \
    _Pragma("unroll") for (int p = 0; p < 2; p++) {                            \
      int r_ = wid * 16 + p * 8 + srow;                                        \
      gload16(gp_ + (long)((h) * 128 + r_) * 1024 + (long)(t) * 64 + scol,     \
              &lds[buf][T][h][(wid * 2 + p) * 512]);                           \
    } }

#define LDA_FRAG(aq)                                                           \
  { _Pragma("unroll") for (int i = 0; i < 4; i++)                              \
      _Pragma("unroll") for (int kk = 0; kk < 2; kk++)                         \
        af[i * 2 + kk] = *(const s16x8*)(Ab + ((aq) * 64 + i * 16 + fr) * 64 + \
                                         ((kk * 32 + fq * 8) ^ xorv)); }

#define LDB_FRAG(bq, arr)                                                      \
  { _Pragma("unroll") for (int j = 0; j < 2; j++)                              \
      _Pragma("unroll") for (int kk = 0; kk < 2; kk++)                         \
        arr[j * 2 + kk] = *(const s16x8*)(Bb + ((wn & 1) * 64 + ((bq) * 2 + j) * 16 + fr) * 64 + \
                                          ((kk * 32 + fq * 8) ^ xorv)); }

#define MM_Q(aq, bq, arr)                                                      \
  { __builtin_amdgcn_s_setprio(1);                                             \
    _Pragma("unroll") for (int i = 0; i < 4; i++)                              \
      _Pragma("unroll") for (int j = 0; j < 2; j++)                            \
        _Pragma("unroll") for (int kk = 0; kk < 2; kk++)                       \
          acc[(aq) * 4 + i][(bq) * 2 + j] = __builtin_amdgcn_mfma_f32_16x16x32_bf16( \
              af[i * 2 + kk], arr[j * 2 + kk], acc[(aq) * 4 + i][(bq) * 2 + j], 0, 0, 0); \
    __builtin_amdgcn_s_setprio(0); }

  f32x4 acc[8][4];
  #pragma unroll
  for (int i = 0; i < 8; i++)
    #pragma unroll
    for (int j = 0; j < 4; j++) acc[i][j] = (f32x4){0.f, 0.f, 0.f, 0.f};

  // prologue: tile0 A0,A1,B0,B1 + tile1 B0,B1
  STAGE(0, 0, 0, 0); STAGE(0, 0, 1, 0); STAGE(0, 1, 0, 0); STAGE(0, 1, 1, 0);
  STAGE(1, 1, 0, 1); STAGE(1, 1, 1, 1);
  asm volatile("s_waitcnt vmcnt(4)" ::: "memory");
  BAR();

  s16x8 af[8], b0f[4], b1f[4];
  for (int t = 0; t < 16; ++t) {
    const int pt = t & 1;
    const unsigned short* Ab = &lds[pt][0][wm][0];
    const unsigned short* Bb = &lds[pt][1][wn >> 1][0];
    // ---- phase 1: quadrant (0,0); stage A0(t+1) ----
    LDA_FRAG(0); LDB_FRAG(0, b0f);
    if (t < 15) STAGE(pt ^ 1, 0, 0, t + 1);
    BAR(); LGKM0();
    MM_Q(0, 0, b0f);
    BAR();
    // ---- phase 2: quadrant (0,1); stage A1(t+1) ----
    LDB_FRAG(1, b1f);
    if (t < 15) STAGE(pt ^ 1, 0, 1, t + 1);
    BAR(); LGKM0();
    MM_Q(0, 1, b1f);
    BAR();
    // ---- phase 3: quadrant (1,0); stage B0(t+2) ----
    LDA_FRAG(1);
    if (t < 14) STAGE(pt, 1, 0, t + 2);
    BAR(); LGKM0();
    MM_Q(1, 0, b0f);
    BAR();
    // ---- phase 4: quadrant (1,1); stage B1(t+2); counted vmcnt ----
    if (t < 14) STAGE(pt, 1, 1, t + 2);
    if (t == 14) { asm volatile("s_waitcnt vmcnt(0)" ::: "memory"); }
    else         { asm volatile("s_waitcnt vmcnt(4)" ::: "memory"); }
    BAR();
    MM_Q(1, 1, b1f);
    BAR();
  }

  // ---- epilogue: split K/V store ----
  const int nbase = nt * 256 + wn * 64;
  const bool kside = (nbase < 1024);
  #pragma unroll
  for (int i = 0; i < 8; i++) {
    const int gm0 = mt * 256 + wm * 128 + i * 16 + fq * 4;
    const int b = gm0 >> 12, mrow = gm0 & 4095;
    #pragma unroll
    for (int j = 0; j < 4; j++) {
      const int n = nbase + j * 16 + fr;
      if (kside) {
        unsigned short* dst = kproj + ((long)b * 4096 + mrow) * 1024 + n;
        #pragma unroll
        for (int q = 0; q < 4; q++) dst[(long)q * 1024] = f2bf(acc[i][j][q]);
      } else {
        ushort4 o;
        o.x = f2bf(acc[i][j][0]); o.y = f2bf(acc[i][j][1]);
        o.z = f2bf(acc[i][j][2]); o.w = f2bf(acc[i][j][3]);
        *(ushort4*)(vt + ((long)b * 1024 + (n - 1024)) * 4096 + mrow) = o;
      }
    }
  }
#undef STAGE
#undef LDA_FRAG
#undef LDB_FRAG
#undef MM_Q
}

// ---------------- rmsnorm rows of length 1024: fp32 -> bf16 (+optional raw bf16) ----------------
__global__ __launch_bounds__(256) void rmsnorm_k(const float* __restrict__ x,
                                                 const float* __restrict__ w,
                                                 unsigned short* __restrict__ y,
                                                 unsigned short* __restrict__ y_raw) {
  const int row = blockIdx.x;
  const int tid = threadIdx.x;
  const float4* xp = (const float4*)(x + (long)row * 1024);
  float4 v = xp[tid];
  float ss = v.x * v.x + v.y * v.y + v.z * v.z + v.w * v.w;
  #pragma unroll
  for (int off = 32; off; off >>= 1) ss += __shfl_xor(ss, off, 64);
  __shared__ float sb[4];
  if ((tid & 63) == 0) sb[tid >> 6] = ss;
  __syncthreads();
  float tot = sb[0] + sb[1] + sb[2] + sb[3];
  float rs = rsqrtf(tot * (1.0f / 1024.0f) + 1e-6f);
  const float4* wp = (const float4*)w;
  float4 wv = wp[tid];
  ushort4 o;
  o.x = f2bf(v.x * rs * wv.x);
  o.y = f2bf(v.y * rs * wv.y);
  o.z = f2bf(v.z * rs * wv.z);
  o.w = f2bf(v.w * rs * wv.w);
  ((ushort4*)y)[(long)row * 256 + tid] = o;
  if (y_raw) {
    ushort4 r;
    r.x = f2bf(v.x); r.y = f2bf(v.y); r.z = f2bf(v.z); r.w = f2bf(v.w);
    ((ushort4*)y_raw)[(long)row * 256 + tid] = r;
  }
}

// ---------------- fused fp32->bf16 converts ----------------
static __device__ __forceinline__ void cvt_chunk(const float* __restrict__ in,
                                                 unsigned short* __restrict__ out, long i) {
  const float4* p = (const float4*)in;
  float4 a = p[i * 2], b = p[i * 2 + 1];
  ushort4 lo, hi;
  lo.x = f2bf(a.x); lo.y = f2bf(a.y); lo.z = f2bf(a.z); lo.w = f2bf(a.w);
  hi.x = f2bf(b.x); hi.y = f2bf(b.y); hi.z = f2bf(b.z); hi.w = f2bf(b.w);
  ushort4* o = (ushort4*)out;
  o[i * 2] = lo;
  o[i * 2 + 1] = hi;
}
// grid 1024: [0,512) -> a (1M elems), [512,1024) -> b (1M elems)
__global__ __launch_bounds__(256) void cvt2_k(const float* __restrict__ a, const float* __restrict__ b,
                                              unsigned short* __restrict__ oa,
                                              unsigned short* __restrict__ ob) {
  int x = blockIdx.x;
  if (x < 512) cvt_chunk(a, oa, (long)x * 256 + threadIdx.x);
  else         cvt_chunk(b, ob, (long)(x - 512) * 256 + threadIdx.x);
}
// grid 3584: [0,512) Wq(1M), [512,2048) wi(3M), [2048,3584) wh(3M)
__global__ __launch_bounds__(256) void cvt3_k(const float* __restrict__ a, const float* __restrict__ b,
                                              const float* __restrict__ c,
                                              unsigned short* __restrict__ oa,
                                              unsigned short* __restrict__ ob,
                                              unsigned short* __restrict__ oc) {
  int x = blockIdx.x;
  if (x < 512)       cvt_chunk(a, oa, (long)x * 256 + threadIdx.x);
  else if (x < 2048) cvt_chunk(b, ob, (long)(x - 512) * 256 + threadIdx.x);
  else               cvt_chunk(c, oc, (long)(x - 2048) * 256 + threadIdx.x);
}

// ---------------- GEMM: C = alpha * A[M][K] @ W[N][K]^T (+bias) ----------------
// EPI: 0 = plain store; 2 = softmax over M(=64) -> bf16 attn + row partials.
// SPLIT: K-split batching. QGH: z=0 -> A/W/C cols[0,1024); z=1..3 -> A2/W2 slab,
//        C cols [z*1024, z*1024+1024), bias2 slab (merged q + gh dispatch).
template <int BM, int BN, int WR, int WC, typename CT, int EPI, int SPLIT, int QGH>
__global__ __launch_bounds__(WR * WC * 64) void gemm_bt(
    const unsigned short* __restrict__ A, const unsigned short* __restrict__ W,
    CT* __restrict__ C, int N, int Klen, int lda, int ldw,
    long sA, long sW, long sC, const float* __restrict__ bias,
    const float* __restrict__ bias2, float alpha, float* __restrict__ rs_part,
    const unsigned short* __restrict__ A2, const unsigned short* __restrict__ W2) {
  constexpr int BK = 64;
  constexpr int NT = WR * WC * 64;
  static_assert(NT == 256, "256 threads");
  constexpr int WSM = BM / WR, WSN = BN / WC;
  constexpr int MR = WSM / 16, NR = WSN / 16;
  constexpr int SEG_A = BM / 8, SEG_W = BN / 8;
  constexpr int PA = SEG_A / 4, PW = SEG_W / 4;
  static_assert(SEG_A % 4 == 0 && SEG_W % 4 == 0, "seg divisibility");
  __shared__ unsigned short As[BM * BK];
  __shared__ unsigned short Ws[BN * BK];
  const int tid = threadIdx.x, lane = tid & 63, wid = tid >> 6;
  const int wr = wid / WC, wc = wid % WC;
  const int tileN = blockIdx.x * BN, tileM = blockIdx.y * BM;
  int coff = 0;
  int zb = 0;
  if constexpr (QGH) {
    const int zz = blockIdx.z;
    if (zz > 0) {
      A = A2;
      W = W2 + (long)(zz - 1) * 1024 * ldw;
      bias = bias2 + (zz - 1) * 1024;
      coff = zz * 1024;
    }
  } else {
    zb = blockIdx.z / SPLIT;
    const int zs = blockIdx.z % SPLIT;
    A += (long)zb * sA + (long)zs * Klen;
    W += (long)zb * sW + (long)zs * Klen;
    C += (long)blockIdx.z * sC;
  }
  const int srow = lane >> 3;
  const int scol = (lane & 7) * 8;
  f32x4 acc[MR][NR];
  #pragma unroll
  for (int i = 0; i < MR; i++)
    #pragma unroll
    for (int j = 0; j < NR; j++) acc[i][j] = (f32x4){0.f, 0.f, 0.f, 0.f};
  const int fr = lane & 15, fq = lane >> 4;

  for (int k0 = 0; k0 < Klen; k0 += BK) {
    #pragma unroll
    for (int p = 0; p < PA; p++) {
      int seg = wid * PA + p;
      gload16(A + (long)(tileM + seg * 8 + srow) * lda + k0 + scol, &As[seg * 512]);
    }
    #pragma unroll
    for (int p = 0; p < PW; p++) {
      int seg = wid * PW + p;
      gload16(W + (long)(tileN + seg * 8 + srow) * ldw + k0 + scol, &Ws[seg * 512]);
    }
    __syncthreads();
    #pragma unroll
    for (int kk = 0; kk < BK; kk += 32) {
      s16x8 af[MR], bf[NR];
      #pragma unroll
      for (int i = 0; i < MR; i++)
        af[i] = *(const s16x8*)(&As[(wr * WSM + i * 16 + fr) * BK + kk + fq * 8]);
      #pragma unroll
      for (int j = 0; j < NR; j++)
        bf[j] = *(const s16x8*)(&Ws[(wc * WSN + j * 16 + fr) * BK + kk + fq * 8]);
      #pragma unroll
      for (int i = 0; i < MR; i++)
        #pragma unroll
        for (int j = 0; j < NR; j++)
          acc[i][j] = __builtin_amdgcn_mfma_f32_16x16x32_bf16(af[i], bf[j], acc[i][j], 0, 0, 0);
    }
    __syncthreads();
  }

  if constexpr (EPI == 2) {
    static_assert(WR == 1 && BM == 64, "softmax epilogue needs full-M wave");
    #pragma unroll
    for (int i = 0; i < MR; i++)
      #pragma unroll
      for (int j = 0; j < NR; j++)
        #pragma unroll
        for (int q = 0; q < 4; q++) acc[i][j][q] *= alpha;
    float inv[NR];
    #pragma unroll
    for (int j = 0; j < NR; j++) {
      float mx = -1e30f;
      #pragma unroll
      for (int i = 0; i < MR; i++)
        #pragma unroll
        for (int q = 0; q < 4; q++) mx = fmaxf(mx, acc[i][j][q]);
      mx = fmaxf(mx, __shfl_xor(mx, 16, 64));
      mx = fmaxf(mx, __shfl_xor(mx, 32, 64));
      float sm = 0.f;
      #pragma unroll
      for (int i = 0; i < MR; i++)
        #pragma unroll
        for (int q = 0; q < 4; q++) {
          float e = __expf(acc[i][j][q] - mx);
          acc[i][j][q] = e;
          sm += e;
        }
      sm += __shfl_xor(sm, 16, 64);
      sm += __shfl_xor(sm, 32, 64);
      inv[j] = 1.f / sm;
    }
    float rp[MR][4];
    #pragma unroll
    for (int i = 0; i < MR; i++)
      #pragma unroll
      for (int q = 0; q < 4; q++) rp[i][q] = 0.f;
    unsigned short* Cs = (unsigned short*)C;
    #pragma unroll
    for (int i = 0; i < MR; i++)
      #pragma unroll
      for (int j = 0; j < NR; j++)
        #pragma unroll
        for (int q = 0; q < 4; q++) {
          float a = acc[i][j][q] * inv[j];
          rp[i][q] += a;
          Cs[(long)(i * 16 + fq * 4 + q) * N + tileN + wc * WSN + j * 16 + fr] = f2bf(a);
        }
    #pragma unroll
    for (int off = 1; off <= 8; off <<= 1)
      #pragma unroll
      for (int i = 0; i < MR; i++)
        #pragma unroll
        for (int q = 0; q < 4; q++) rp[i][q] += __shfl_xor(rp[i][q], off, 64);
    if (fr == 0) {
      const int rld = gridDim.x * WC;
      #pragma unroll
      for (int i = 0; i < MR; i++)
        #pragma unroll
        for (int q = 0; q < 4; q++)
          rs_part[((long)zb * 64 + i * 16 + fq * 4 + q) * rld + blockIdx.x * WC + wc] = rp[i][q];
    }
    return;
  }

  #pragma unroll
  for (int i = 0; i < MR; i++) {
    const int mbase = tileM + wr * WSM + i * 16 + fq * 4;
    #pragma unroll
    for (int j = 0; j < NR; j++) {
      const int n = tileN + wc * WSN + j * 16 + fr;
      const float bv = bias ? bias[n] : 0.f;
      #pragma unroll
      for (int q = 0; q < 4; q++) {
        float v = acc[i][j][q] * alpha + bv;
        if constexpr (sizeof(CT) == 2)
          C[(long)(mbase + q) * N + coff + n] = f2bf(v);
        else
          C[(long)(mbase + q) * N + coff + n] = v;
      }
    }
  }
}

// ---- reduce 8 bf16 K-splits; in-block rowsum of rs_part -> rowinv; scale; cast bf16 ----
// block = one (b,k) row (512 blocks x 256 threads, 4 elems/thread)
__global__ __launch_bounds__(256) void upd_reduce_k(const unsigned short* __restrict__ part,
                                                    const float* __restrict__ rs_part,
                                                    unsigned short* __restrict__ out) {
  const int row = blockIdx.x;  // b*64 + k
  const int tid = threadIdx.x;
  float s = (tid < 128) ? rs_part[(long)row * 128 + tid] : 0.f;
  #pragma unroll
  for (int off = 32; off; off >>= 1) s += __shfl_xor(s, off, 64);
  __shared__ float sb[4];
  if ((tid & 63) == 0) sb[tid >> 6] = s;
  __syncthreads();
  const float inv = 1.f / (sb[0] + sb[1] + sb[2] + sb[3] + 1e-6f);
  const unsigned short* base =
      part + (long)(row >> 6) * 8 * 65536 + (long)(row & 63) * 1024 + tid * 4;
  float ax = 0.f, ay = 0.f, az = 0.f, aw = 0.f;
  #pragma unroll
  for (int sp = 0; sp < 8; sp++) {
    ushort4 v = *(const ushort4*)(base + (long)sp * 65536);
    ax += bf2f(v.x); ay += bf2f(v.y); az += bf2f(v.z); aw += bf2f(v.w);
  }
  ushort4 o;
  o.x = f2bf(ax * inv); o.y = f2bf(ay * inv);
  o.z = f2bf(az * inv); o.w = f2bf(aw * inv);
  ((ushort4*)out)[(long)row * 256 + tid] = o;
}

// ---- GRU combine (bf16 gi / gh-in-qgh) + fused rmsnorm of the new slots ----
__global__ __launch_bounds__(256) void gru_k(const unsigned short* __restrict__ gi,
                                             const unsigned short* __restrict__ qgh,
                                             const float* __restrict__ h,
                                             const float* __restrict__ snw,
                                             float* __restrict__ out,
                                             unsigned short* __restrict__ out_bf,
                                             unsigned short* __restrict__ sn_out) {
  const int r = blockIdx.x;
  const int tid = threadIdx.x;
  const int c = tid * 4;
  const unsigned short* gip = gi + (long)r * 3072;
  const unsigned short* ghp = qgh + (long)r * 4096 + 1024;
  ushort4 iru = *(const ushort4*)(gip + c);
  ushort4 izu = *(const ushort4*)(gip + 1024 + c);
  ushort4 inu = *(const ushort4*)(gip + 2048 + c);
  ushort4 hru = *(const ushort4*)(ghp + c);
  ushort4 hzu = *(const ushort4*)(ghp + 1024 + c);
  ushort4 hnu = *(const ushort4*)(ghp + 2048 + c);
  float4 hv = *(const float4*)(h + (long)r * 1024 + c);
  float4 o;
  { float rr = sigm(bf2f(iru.x) + bf2f(hru.x)), zz = sigm(bf2f(izu.x) + bf2f(hzu.x));
    float nn = tanhf(bf2f(inu.x) + rr * bf2f(hnu.x)); o.x = (1.f - zz) * nn + zz * hv.x; }
  { float rr = sigm(bf2f(iru.y) + bf2f(hru.y)), zz = sigm(bf2f(izu.y) + bf2f(hzu.y));
    float nn = tanhf(bf2f(inu.y) + rr * bf2f(hnu.y)); o.y = (1.f - zz) * nn + zz * hv.y; }
  { float rr = sigm(bf2f(iru.z) + bf2f(hru.z)), zz = sigm(bf2f(izu.z) + bf2f(hzu.z));
    float nn = tanhf(bf2f(inu.z) + rr * bf2f(hnu.z)); o.z = (1.f - zz) * nn + zz * hv.z; }
  { float rr = sigm(bf2f(iru.w) + bf2f(hru.w)), zz = sigm(bf2f(izu.w) + bf2f(hzu.w));
    float nn = tanhf(bf2f(inu.w) + rr * bf2f(hnu.w)); o.w = (1.f - zz) * nn + zz * hv.w; }
  *(float4*)(out + (long)r * 1024 + c) = o;
  ushort4 ob;
  ob.x = f2bf(o.x); ob.y = f2bf(o.y); ob.z = f2bf(o.z); ob.w = f2bf(o.w);
  *(ushort4*)(out_bf + (long)r * 1024 + c) = ob;
  float ss = o.x * o.x + o.y * o.y + o.z * o.z + o.w * o.w;
  #pragma unroll
  for (int off = 32; off; off >>= 1) ss += __shfl_xor(ss, off, 64);
  __shared__ float sb[4];
  if ((tid & 63) == 0) sb[tid >> 6] = ss;
  __syncthreads();
  const float tot = sb[0] + sb[1] + sb[2] + sb[3];
  const float rs = rsqrtf(tot * (1.0f / 1024.0f) + 1e-6f);
  float4 wv = *(const float4*)(snw + c);
  ushort4 so;
  so.x = f2bf(o.x * rs * wv.x); so.y = f2bf(o.y * rs * wv.y);
  so.z = f2bf(o.z * rs * wv.z); so.w = f2bf(o.w * rs * wv.w);
  *(ushort4*)(sn_out + (long)r * 1024 + c) = so;
}

extern "C" void kernel_launch(void* const* d_in, const int* in_sizes, int n_in,
                              void* d_out, int out_size, void* d_ws, size_t ws_size,
                              hipStream_t stream) {
  const float* slots_in = (const float*)d_in[0];
  const float* P        = (const float*)d_in[1];
  const float* Wq       = (const float*)d_in[2];
  const float* Wk       = (const float*)d_in[3];
  const float* Wv       = (const float*)d_in[4];
  const float* wi       = (const float*)d_in[5];
  const float* wh       = (const float*)d_in[6];
  const float* bi       = (const float*)d_in[7];
  const float* bh       = (const float*)d_in[8];
  const float* snw      = (const float*)d_in[9];
  const float* inw      = (const float*)d_in[10];

  const size_t MB = 1024ull * 1024ull;
  char* ws = (char*)d_ws;
  unsigned short* kproj = (unsigned short*)(ws + 0);        // 64MB [b][m][e] bf16
  unsigned short* vt    = (unsigned short*)(ws + 64 * MB);  // 64MB [b][e][m] bf16
  char* S               = ws + 128 * MB;                    // 64MB reuse region
  unsigned short* Pn    = (unsigned short*)(S);             // prologue only (64MB)
  unsigned short* sn    = (unsigned short*)(S);             // 1MB
  unsigned short* qgh   = (unsigned short*)(S + 1 * MB);    // 4MB [512][4096]: q | gh
  unsigned short* attnb = (unsigned short*)(S + 5 * MB);    // 4MB
  unsigned short* updb  = (unsigned short*)(S + 9 * MB);    // 1MB
  unsigned short* slotsb= (unsigned short*)(S + 10 * MB);   // 1MB
  unsigned short* gi_b  = (unsigned short*)(S + 11 * MB);   // 3MB [512][3072]
  unsigned short* Cpart = (unsigned short*)(S + 14 * MB);   // 8MB bf16 [64][64][1024]
  float* rs_part        = (float*)(S + 22 * MB);            // 256KB
  unsigned short* wq_b  = (unsigned short*)(S + 23 * MB);   // 2MB
  unsigned short* wi_b  = (unsigned short*)(S + 25 * MB);   // 6MB
  unsigned short* wh_b  = (unsigned short*)(S + 31 * MB);   // 6MB
  unsigned short* wk_b  = (unsigned short*)(ws + 192 * MB); // 2MB  } combined W [2048][1024]
  unsigned short* wv_b  = (unsigned short*)(ws + 194 * MB); // 2MB  }
  float* slots          = (float*)(ws + 196 * MB);          // 2MB

  // ---- prologue ----
  cvt2_k<<<1024, 256, 0, stream>>>(Wk, Wv, wk_b, wv_b);
  rmsnorm_k<<<32768, 256, 0, stream>>>(P, inw, Pn, nullptr);
  // combined K+V projection: M=32768, N=2048, K=1024 (8-phase 256^2)
  proj_k<<<1024, 512, 0, stream>>>(Pn, wk_b, kproj, vt);
  cvt3_k<<<3584, 256, 0, stream>>>(Wq, wi, wh, wq_b, wi_b, wh_b);
  // fused: sn = rmsnorm(slots_in), slotsb = bf16(slots_in)
  rmsnorm_k<<<512, 256, 0, stream>>>(slots_in, snw, sn, slotsb);

  // ---- 3 iterations (6 dispatches each) ----
  for (int it = 0; it < 3; ++it) {
    // merged q+gh: z=0 -> q = sn@Wq^T into qgh[:, :1024];
    //              z=1..3 -> gh slab = slotsb@wh^T+bh into qgh[:, z*1024 ..)
    gemm_bt<64, 64, 2, 2, unsigned short, 0, 1, 1>
        <<<dim3(16, 8, 4), 256, 0, stream>>>(sn, wq_b, qgh, 4096, 1024, 1024, 1024,
                                             0, 0, 0, nullptr, bh, 1.f, nullptr,
                                             slotsb, wh_b);
    // attn[b][k][m] = softmax_k((q_b @ kproj_b^T)/32) + row partials
    gemm_bt<64, 128, 1, 4, unsigned short, 2, 1, 0>
        <<<dim3(32, 1, 8), 256, 0, stream>>>(qgh, kproj, attnb, 4096, 1024, 4096, 1024,
                                             64L * 4096, 4096L * 1024, 64L * 4096,
                                             nullptr, nullptr, 0.03125f, rs_part,
                                             nullptr, nullptr);
    // updates partials (bf16): attn_b @ vt_b^T, K=4096 split 8x512 (1024 blocks)
    gemm_bt<64, 64, 2, 2, unsigned short, 0, 8, 0>
        <<<dim3(16, 1, 64), 256, 0, stream>>>(attnb, vt, Cpart, 1024, 512, 4096, 4096,
                                              64L * 4096, 1024L * 4096, 64L * 1024,
                                              nullptr, nullptr, 1.f, nullptr,
                                              nullptr, nullptr);
    upd_reduce_k<<<512, 256, 0, stream>>>(Cpart, rs_part, updb);
    // gi = updb @ wi^T + bi -> bf16 [512][3072]
    gemm_bt<64, 64, 2, 2, unsigned short, 0, 1, 0>
        <<<dim3(48, 8, 1), 256, 0, stream>>>(updb, wi_b, gi_b, 3072, 1024, 1024, 1024,
                                             0, 0, 0, bi, nullptr, 1.f, nullptr,
                                             nullptr, nullptr);
    const float* hsrc = (it == 0) ? slots_in : slots;
    float* dst = (it == 2) ? (float*)d_out : slots;
    gru_k<<<512, 256, 0, stream>>>(gi_b, qgh, hsrc, snw, dst, slotsb, sn);
  }
}